// Round 4
// baseline (701.951 us; speedup 1.0000x reference)
//
#include <hip/hip_runtime.h>
#include <math.h>

// Problem constants
#define BSZ 64
#define NPTS 512
#define DIM 256
#define MROWS 32768      // BSZ*NPTS
#define TOTROWS 65536
#define BIGF 1.0e9f

typedef __bf16 bf16x8 __attribute__((ext_vector_type(8)));
typedef float  f32x4  __attribute__((ext_vector_type(4)));

// ws layout (float offsets)
#define KB_OFF    0ull          // K bf16: ushort[16777216]
#define E_OFF     8388608ull    // Ebf: ushort[16777216]
#define H_OFF     16777216ull   // Hbf: ushort[16777216]
#define NORM_OFF  25165824ull   // 65536 f32
#define U_OFF     25231360ull   // 32768 f32
#define V_OFF     25264128ull   // 32768 f32
#define ARGA_OFF  25296896ull   // 32768 int
#define ARGB_OFF  25329664ull   // 32768 int
#define ACC_OFF   25362432ull   // 512 f32 (321 used)
#define WT1_OFF   25362944ull   // ushort[65536]
#define WT2_OFF   25395712ull   // ushort[65536]
#define CS_OFF    25428480ull   // 524288 f32: cs[2][64][8][512]
#define CTR_OFF   25952768ull   // 1024 int

#define ACC_PA   0
#define ACC_IN   1     // 64 slots
#define ACC_SUP  65    // 256 slots
#define ACC_CNT  321

#define SINK_G   8     // blocks per batch in sinkhorn

__device__ __forceinline__ float bf2f(unsigned short h) {
    return __uint_as_float(((unsigned int)h) << 16);
}
__device__ __forceinline__ unsigned short f2bf(float f) {
    unsigned int u = __float_as_uint(f);
    u = (u + 0x7FFFu + ((u >> 16) & 1u)) >> 16;
    return (unsigned short)u;
}

// re-entrant
__device__ __forceinline__ float block_reduce_256(float val) {
    __shared__ float sh[4];
    int lane = threadIdx.x & 63;
    int wv = threadIdx.x >> 6;
    __syncthreads();
#pragma unroll
    for (int off = 32; off > 0; off >>= 1) val += __shfl_down(val, off, 64);
    if (lane == 0) sh[wv] = val;
    __syncthreads();
    float r = 0.f;
    if (wv == 0 && lane < 4) r = sh[lane];
    if (wv == 0) {
        r += __shfl_down(r, 2, 64);
        r += __shfl_down(r, 1, 64);
    }
    return r;  // valid in thread 0
}

__global__ void zero_misc_kernel(float* acc, int* ctr) {
    int t = blockIdx.x * 256 + threadIdx.x;
    if (t < ACC_CNT) acc[t] = 0.f;
    if (t < 1024) ctr[t] = 0;
}

__global__ __launch_bounds__(256) void argmax_pa_kernel(
    const float* __restrict__ la, const float* __restrict__ lb,
    const float* __restrict__ pa, int* __restrict__ argA, int* __restrict__ argB,
    float* __restrict__ acc) {
    int i = blockIdx.x * 256 + threadIdx.x;
    float4 a = *(const float4*)&la[(size_t)i * 4];
    float av[4] = {a.x, a.y, a.z, a.w};
    int ba = 0; float bv = av[0];
#pragma unroll
    for (int c = 1; c < 4; ++c) if (av[c] > bv) { bv = av[c]; ba = c; }
    argA[i] = ba;
    float4 b = *(const float4*)&lb[(size_t)i * 4];
    float bw[4] = {b.x, b.y, b.z, b.w};
    int bbi = 0; float bm = bw[0];
#pragma unroll
    for (int c = 1; c < 4; ++c) if (bw[c] > bm) { bm = bw[c]; bbi = c; }
    argB[i] = bbi;
    float p = pa[i];
#pragma unroll
    for (int off = 32; off > 0; off >>= 1) p += __shfl_down(p, off, 64);
    if ((threadIdx.x & 63) == 0) atomicAdd(&acc[ACC_PA], p);
}

// W[256][256] f32 -> Wt[n][k] bf16 (transposed)
__global__ __launch_bounds__(256) void cast_wt_kernel(
    const float* __restrict__ W, unsigned short* __restrict__ Wt) {
    __shared__ float tile[16][17];
    int tx = threadIdx.x & 15, ty = threadIdx.x >> 4;
    int bx = blockIdx.x, by = blockIdx.y;
    tile[ty][tx] = W[(size_t)(by * 16 + ty) * 256 + bx * 16 + tx];
    __syncthreads();
    Wt[(size_t)(bx * 16 + ty) * 256 + by * 16 + tx] = f2bf(tile[tx][ty]);
}

// Fused: Y(bf16) = LN(leaky(X @ W + bias)) * g + be, optional row sq-norms.
// X is f32 (IN_F32) or bf16. Tile 64 rows x 256 cols (full LN row in-block).
// MFMA 16x16x32 bf16; C layout col=lane&15, row=(lane>>4)*4+reg (verified m89/m91).
template <bool IN_F32>
__global__ __launch_bounds__(256) void gemm_ln_kernel(
    const void* __restrict__ Xv, const unsigned short* __restrict__ Wt,
    const float* __restrict__ bias, const float* __restrict__ gam,
    const float* __restrict__ bet, unsigned short* __restrict__ Y,
    float* __restrict__ norms) {
    __shared__ unsigned short Xs[64 * 40];
    __shared__ unsigned short Ws[256 * 40];
    const int t = threadIdx.x;
    const int L = t & 63, wv = t >> 6;
    const int q = L >> 4, n = L & 15;
    const size_t row0 = (size_t)blockIdx.x * 64;
    f32x4 acc[16];
#pragma unroll
    for (int nt = 0; nt < 16; ++nt) acc[nt] = (f32x4){0.f, 0.f, 0.f, 0.f};

    for (int k0 = 0; k0 < 256; k0 += 32) {
        {
            int r = t >> 2, seg = t & 3;
            if (IN_F32) {
                const float* Xf = (const float*)Xv;
                float4 aa = *(const float4*)&Xf[(row0 + r) * 256 + k0 + seg * 8];
                float4 bb = *(const float4*)&Xf[(row0 + r) * 256 + k0 + seg * 8 + 4];
                uint4 pk;
                pk.x = (unsigned)f2bf(aa.x) | ((unsigned)f2bf(aa.y) << 16);
                pk.y = (unsigned)f2bf(aa.z) | ((unsigned)f2bf(aa.w) << 16);
                pk.z = (unsigned)f2bf(bb.x) | ((unsigned)f2bf(bb.y) << 16);
                pk.w = (unsigned)f2bf(bb.z) | ((unsigned)f2bf(bb.w) << 16);
                *(uint4*)&Xs[r * 40 + seg * 8] = pk;
            } else {
                const unsigned short* Xh = (const unsigned short*)Xv;
                *(uint4*)&Xs[r * 40 + seg * 8] =
                    *(const uint4*)&Xh[(row0 + r) * 256 + k0 + seg * 8];
            }
#pragma unroll
            for (int it = 0; it < 4; ++it) {
                int nn = (t >> 2) + it * 64;
                *(uint4*)&Ws[nn * 40 + seg * 8] =
                    *(const uint4*)&Wt[(size_t)nn * 256 + k0 + seg * 8];
            }
        }
        __syncthreads();
        bf16x8 av = *(const bf16x8*)&Xs[(wv * 16 + n) * 40 + q * 8];
#pragma unroll
        for (int nt = 0; nt < 16; ++nt) {
            bf16x8 bv = *(const bf16x8*)&Ws[(nt * 16 + n) * 40 + q * 8];
            acc[nt] = __builtin_amdgcn_mfma_f32_16x16x32_bf16(av, bv, acc[nt], 0, 0, 0);
        }
        __syncthreads();
    }
    // epilogue: bias + leaky, row stats via 16-lane xor-shuffle (bits 0..3 stay in n-group)
    float s[4] = {0.f, 0.f, 0.f, 0.f}, sq[4] = {0.f, 0.f, 0.f, 0.f};
#pragma unroll
    for (int nt = 0; nt < 16; ++nt) {
        float bv = bias[nt * 16 + n];
#pragma unroll
        for (int r = 0; r < 4; ++r) {
            float h = acc[nt][r] + bv;
            h = h >= 0.f ? h : 0.01f * h;
            acc[nt][r] = h;
            s[r] += h; sq[r] += h * h;
        }
    }
#pragma unroll
    for (int r = 0; r < 4; ++r) {
#pragma unroll
        for (int off = 8; off >= 1; off >>= 1) {
            s[r] += __shfl_xor(s[r], off, 64);
            sq[r] += __shfl_xor(sq[r], off, 64);
        }
    }
    float mean[4], inv[4];
#pragma unroll
    for (int r = 0; r < 4; ++r) {
        mean[r] = s[r] * (1.f / 256.f);
        float var = fmaxf(sq[r] * (1.f / 256.f) - mean[r] * mean[r], 0.f);
        inv[r] = rsqrtf(var + 1e-5f);
    }
    float nr[4] = {0.f, 0.f, 0.f, 0.f};
#pragma unroll
    for (int nt = 0; nt < 16; ++nt) {
        float gv = gam[nt * 16 + n], ev = bet[nt * 16 + n];
#pragma unroll
        for (int r = 0; r < 4; ++r) {
            float o = (acc[nt][r] - mean[r]) * inv[r] * gv + ev;
            unsigned short ob = f2bf(o);
            size_t row = row0 + wv * 16 + q * 4 + r;
            Y[row * 256 + nt * 16 + n] = ob;
            float orr = bf2f(ob);
            nr[r] += orr * orr;
        }
    }
    if (norms) {
#pragma unroll
        for (int r = 0; r < 4; ++r) {
#pragma unroll
            for (int off = 8; off >= 1; off >>= 1) nr[r] += __shfl_xor(nr[r], off, 64);
        }
        if (n == 0) {
#pragma unroll
            for (int r = 0; r < 4; ++r)
                norms[row0 + wv * 16 + q * 4 + r] = nr[r];
        }
    }
}

// cdist via MFMA + in/out loss partial + K(bf16) = exp(-2*cost)
__global__ __launch_bounds__(256) void cost_mfma_kernel(
    const unsigned short* __restrict__ E, const float* __restrict__ norms,
    const int* __restrict__ argA, const int* __restrict__ argB,
    const float* __restrict__ pa, const float* __restrict__ pb,
    unsigned short* __restrict__ Kb16, float* __restrict__ acc) {
    __shared__ unsigned short As[64 * 40];
    __shared__ unsigned short Bs[64 * 40];
    const int t = threadIdx.x;
    const int L = t & 63, wv = t >> 6;
    const int q = L >> 4, n = L & 15;
    const int b = blockIdx.z;
    const int i0 = blockIdx.y * 64, j0 = blockIdx.x * 64;
    const unsigned short* eA = E + (size_t)b * 512 * 256;
    const unsigned short* eB = E + (size_t)(32768 + b * 512) * 256;
    f32x4 dot[4];
#pragma unroll
    for (int nt = 0; nt < 4; ++nt) dot[nt] = (f32x4){0.f, 0.f, 0.f, 0.f};

    for (int k0 = 0; k0 < 256; k0 += 32) {
        int r = t >> 2, seg = t & 3;
        *(uint4*)&As[r * 40 + seg * 8] =
            *(const uint4*)&eA[(size_t)(i0 + r) * 256 + k0 + seg * 8];
        *(uint4*)&Bs[r * 40 + seg * 8] =
            *(const uint4*)&eB[(size_t)(j0 + r) * 256 + k0 + seg * 8];
        __syncthreads();
        bf16x8 av = *(const bf16x8*)&As[(wv * 16 + n) * 40 + q * 8];
#pragma unroll
        for (int nt = 0; nt < 4; ++nt) {
            bf16x8 bv = *(const bf16x8*)&Bs[(nt * 16 + n) * 40 + q * 8];
            dot[nt] = __builtin_amdgcn_mfma_f32_16x16x32_bf16(av, bv, dot[nt], 0, 0, 0);
        }
        __syncthreads();
    }
    int base_row = i0 + wv * 16 + q * 4;
    float nA[4], pA[4]; int cA[4];
#pragma unroll
    for (int r = 0; r < 4; ++r) {
        nA[r] = norms[b * 512 + base_row + r];
        pA[r] = pa[b * 512 + base_row + r];
        cA[r] = argA[b * 512 + base_row + r];
    }
    float part = 0.f;
#pragma unroll
    for (int nt = 0; nt < 4; ++nt) {
        int col = j0 + nt * 16 + n;
        float nB = norms[32768 + b * 512 + col];
        float pB = pb[b * 512 + col];
        int cB = argB[b * 512 + col];
#pragma unroll
        for (int r = 0; r < 4; ++r) {
            float d2 = nA[r] + nB - 2.f * dot[nt][r];
            float c = sqrtf(fmaxf(d2, 0.f));
            float pm = pA[r] * pB;
            float cc = c + (BIGF - BIGF * pm);
            float sgn = (cA[r] == cB) ? 1.f : -1.f;
            part += cc * sgn * pm;
            Kb16[((size_t)b * 512 + base_row + r) * 512 + col] = f2bf(expf(-2.f * cc));
        }
    }
    float tot = block_reduce_256(part);
    if (threadIdx.x == 0) atomicAdd(&acc[ACC_IN + b], tot);
}

// split Sinkhorn: 8 blocks per batch, 64 rows each; double-buffered colsum
// partials in global + one device-scope spin barrier per iteration.
__global__ __launch_bounds__(256) void sinkhorn_split_kernel(
    const unsigned short* __restrict__ Kb16, float* __restrict__ u, float* __restrict__ v,
    float* __restrict__ cs, int* __restrict__ ctr) {
    const int blk = blockIdx.x;
    const int b = blk >> 3, g = blk & 7;
    const unsigned short* Kb = Kb16 + (size_t)b * 262144 + (size_t)g * 64 * 512;
    __shared__ float uo[64];
    __shared__ float vv[512];
    const int t = threadIdx.x;
    const int l = t & 63, wv = t >> 6;
    int* myctr = ctr + b * 16;
    if (t < 64) uo[t] = 1.f / 512.f;
    __syncthreads();
    for (int it = 0; it < 10; ++it) {
        int buf = it & 1;
        // v-step partial col sums over own 64 rows; thread covers cols 2t,2t+1
        float s0 = 0.f, s1 = 0.f;
        {
            const unsigned short* base = Kb + t * 2;
#pragma unroll 8
            for (int i = 0; i < 64; ++i) {
                unsigned int w = *(const unsigned int*)(base + (size_t)i * 512);
                float ui = uo[i];
                s0 = fmaf(__uint_as_float(w << 16), ui, s0);
                s1 = fmaf(__uint_as_float(w & 0xFFFF0000u), ui, s1);
            }
        }
        float* dst = cs + (((size_t)buf * 64 + b) * 8 + g) * 512;
        __hip_atomic_store(&dst[t * 2], s0, __ATOMIC_RELAXED, __HIP_MEMORY_SCOPE_AGENT);
        __hip_atomic_store(&dst[t * 2 + 1], s1, __ATOMIC_RELAXED, __HIP_MEMORY_SCOPE_AGENT);
        __syncthreads();
        if (t == 0) {
            __threadfence();
            atomicAdd(&myctr[it], 1);
            while (__hip_atomic_load(&myctr[it], __ATOMIC_ACQUIRE,
                                     __HIP_MEMORY_SCOPE_AGENT) < SINK_G) {
                __builtin_amdgcn_s_sleep(1);
            }
        }
        __syncthreads();
        // gather 8 partials -> v
        {
            const float* srcb = cs + (((size_t)buf * 64 + b) * 8) * 512;
            float a0 = 0.f, a1 = 0.f;
#pragma unroll
            for (int gg = 0; gg < 8; ++gg) {
                a0 += __hip_atomic_load(&srcb[gg * 512 + t * 2], __ATOMIC_RELAXED,
                                        __HIP_MEMORY_SCOPE_AGENT);
                a1 += __hip_atomic_load(&srcb[gg * 512 + t * 2 + 1], __ATOMIC_RELAXED,
                                        __HIP_MEMORY_SCOPE_AGENT);
            }
            vv[t * 2] = (1.f / 512.f) / a0;
            vv[t * 2 + 1] = (1.f / 512.f) / a1;
        }
        __syncthreads();
        // u-step: wave wv handles rows wv*16..+15 of own 64
        float4 va = *(const float4*)&vv[l * 8];
        float4 vb = *(const float4*)&vv[l * 8 + 4];
        for (int rr = 0; rr < 16; ++rr) {
            int row = wv * 16 + rr;
            uint4 w4 = *(const uint4*)(Kb + (size_t)row * 512 + l * 8);
            float sr = 0.f;
            sr = fmaf(__uint_as_float(w4.x << 16), va.x, sr);
            sr = fmaf(__uint_as_float(w4.x & 0xFFFF0000u), va.y, sr);
            sr = fmaf(__uint_as_float(w4.y << 16), va.z, sr);
            sr = fmaf(__uint_as_float(w4.y & 0xFFFF0000u), va.w, sr);
            sr = fmaf(__uint_as_float(w4.z << 16), vb.x, sr);
            sr = fmaf(__uint_as_float(w4.z & 0xFFFF0000u), vb.y, sr);
            sr = fmaf(__uint_as_float(w4.w << 16), vb.z, sr);
            sr = fmaf(__uint_as_float(w4.w & 0xFFFF0000u), vb.w, sr);
#pragma unroll
            for (int off = 32; off > 0; off >>= 1) sr += __shfl_down(sr, off, 64);
            if (l == 0) uo[row] = (1.f / 512.f) / sr;
        }
        __syncthreads();
    }
    if (t < 64) u[(size_t)b * 512 + g * 64 + t] = uo[t];
    if (g == 0) {
        v[(size_t)b * 512 + t * 2] = vv[t * 2];
        v[(size_t)b * 512 + t * 2 + 1] = vv[t * 2 + 1];
    }
}

// sup loss on bf16 K
__global__ __launch_bounds__(256) void sup_kernel(
    const unsigned short* __restrict__ Kb16, const float* __restrict__ u,
    const float* __restrict__ v, const float* __restrict__ rel,
    const float* __restrict__ pa, float* __restrict__ acc) {
    const int nthreads = 4096 * 256;
    int tid = blockIdx.x * 256 + threadIdx.x;
    float part = 0.f;
#pragma unroll
    for (int k = 0; k < 4; ++k) {
        int i4 = tid + k * nthreads;
        int e = i4 * 4;
        int b = e >> 18;
        int i = (e >> 9) & 511;
        int j0 = e & 511;
        ushort4 K4 = *(const ushort4*)&Kb16[(size_t)i4 * 4];
        float4 r4 = *(const float4*)&rel[(size_t)i4 * 4];
        float4 v4 = *(const float4*)&v[b * 512 + j0];
        float ui = u[b * 512 + i] * 512.f;
        float pai = pa[b * 512 + i];
        float d0 = ui * bf2f(K4.x) * v4.x - r4.x;
        float d1 = ui * bf2f(K4.y) * v4.y - r4.y;
        float d2 = ui * bf2f(K4.z) * v4.z - r4.z;
        float d3 = ui * bf2f(K4.w) * v4.w - r4.w;
        part += (d0 * d0 + d1 * d1 + d2 * d2 + d3 * d3) * pai;
    }
    float tot = block_reduce_256(part);
    if (threadIdx.x == 0) atomicAdd(&acc[ACC_SUP + (blockIdx.x & 255)], tot);
}

__global__ __launch_bounds__(256) void final_kernel(const float* __restrict__ acc,
                                                    float* __restrict__ out) {
    int t = threadIdx.x;
    float vin = (t < 64) ? acc[ACC_IN + t] : 0.f;
    float sIn = block_reduce_256(vin);
    float vsup = acc[ACC_SUP + t];
    float sSup = block_reduce_256(vsup);
    if (t == 0)
        out[0] = sIn * (1.f / 16777216.f) + 10.f * sSup / acc[ACC_PA];
}

extern "C" void kernel_launch(void* const* d_in, const int* in_sizes, int n_in,
                              void* d_out, int out_size, void* d_ws, size_t ws_size,
                              hipStream_t stream) {
    const float* la  = (const float*)d_in[0];
    const float* lb  = (const float*)d_in[1];
    const float* xA  = (const float*)d_in[2];
    const float* xB  = (const float*)d_in[3];
    const float* rel = (const float*)d_in[4];
    const float* pa  = (const float*)d_in[5];
    const float* pb  = (const float*)d_in[6];
    const float* W1  = (const float*)d_in[7];
    const float* b1  = (const float*)d_in[8];
    const float* g1  = (const float*)d_in[9];
    const float* be1 = (const float*)d_in[10];
    const float* W2  = (const float*)d_in[11];
    const float* b2  = (const float*)d_in[12];
    const float* g2  = (const float*)d_in[13];
    const float* be2 = (const float*)d_in[14];
    float* out = (float*)d_out;

    float* ws = (float*)d_ws;
    unsigned short* Kb16 = (unsigned short*)(ws + KB_OFF);
    unsigned short* Ebf  = (unsigned short*)(ws + E_OFF);
    unsigned short* Hbf  = (unsigned short*)(ws + H_OFF);
    float* norms = ws + NORM_OFF;
    float* u     = ws + U_OFF;
    float* v     = ws + V_OFF;
    int* argA    = (int*)(ws + ARGA_OFF);
    int* argB    = (int*)(ws + ARGB_OFF);
    float* acc   = ws + ACC_OFF;
    unsigned short* Wt1 = (unsigned short*)(ws + WT1_OFF);
    unsigned short* Wt2 = (unsigned short*)(ws + WT2_OFF);
    float* cs    = ws + CS_OFF;
    int* ctr     = (int*)(ws + CTR_OFF);

    zero_misc_kernel<<<4, 256, 0, stream>>>(acc, ctr);
    argmax_pa_kernel<<<128, 256, 0, stream>>>(la, lb, pa, argA, argB, acc);

    cast_wt_kernel<<<dim3(16, 16), 256, 0, stream>>>(W1, Wt1);
    cast_wt_kernel<<<dim3(16, 16), 256, 0, stream>>>(W2, Wt2);

    // layer 1 (fused cast+gemm+bias+leaky+LN): f32 in, bf16 out
    gemm_ln_kernel<true><<<512, 256, 0, stream>>>(xA, Wt1, b1, g1, be1, Hbf, nullptr);
    gemm_ln_kernel<true><<<512, 256, 0, stream>>>(xB, Wt1, b1, g1, be1,
                                                  Hbf + (size_t)MROWS * DIM, nullptr);
    // layer 2: bf16 in, bf16 out + row norms
    gemm_ln_kernel<false><<<1024, 256, 0, stream>>>(Hbf, Wt2, b2, g2, be2, Ebf, norms);

    // cost + K(bf16)
    cost_mfma_kernel<<<dim3(8, 8, 64), 256, 0, stream>>>(Ebf, norms, argA, argB, pa, pb,
                                                         Kb16, acc);

    // sinkhorn: 8 blocks/batch, spin-barrier coupled
    sinkhorn_split_kernel<<<512, 256, 0, stream>>>(Kb16, u, v, cs, ctr);

    sup_kernel<<<4096, 256, 0, stream>>>(Kb16, u, v, rel, pa, acc);
    final_kernel<<<1, 256, 0, stream>>>(acc, out);
}